// Round 13
// baseline (892.251 us; speedup 1.0000x reference)
//
#include <hip/hip_runtime.h>

// RSNN forward: B=128, T=512, IN=128, N=512, OUT=128, fp32 in/out.
// d_out = [vt (128*513*512) | zt (128*513*512) | out (128*512*128)] fp32.
//
// Pipeline:
//  1. jwm:  G = W@J, M = W@Bw (fp32) -> ws
//  2. pack: J->i8 16-way k-split frags; Bw->bf16 hi/lo; G,M->bf16 frags -> ws
//  3. xpd:  D = thr(U) - X@Bw^T -> vt region, SLOT layout (D[b][t] at slot (b,t+1))
//  4. recur (128 WGs x 1024 thr = 16 waves = 4/SIMD, 1 batch/WG):
//     16-way k-split i8 dot4 recurrence. Lane l: slice kap=l&15 (32 elems,
//     2 x ds_read_b128, <=2-way banks), group g=l>>4 owns 8 neurons,
//     jr = 64 VGPRs. 4-stage DPP reduce (xor1,xor2,half-mirror,row-mirror)
//     + cndmask select. Lane pairs (kap,kap+8) duplicate a neuron: l&8==0
//     stores v, l&8==1 stores z (bulk, after all D uses; z-derived opaque
//     zero orders stores after D consumption). D-refill in-loop per step.
//  5. outk: out = tanh(vt)@G^T + X@M^T via MFMA.

typedef __attribute__((ext_vector_type(8))) short short8x;
typedef __attribute__((ext_vector_type(4))) float f32x4;

// ---- workspace layout (bytes) ----
#define OFF_JQK  (0u)        // J i8 k-split frags: 16384 * 16B = 262144
#define OFF_BWH  (262144u)   // Bw hi bf16 frags: 131072
#define OFF_BWL  (393216u)
#define OFF_G    (524288u)   // G fp32 [128][512] = 262144
#define OFF_M    (786432u)   // M fp32 [128][128] = 65536
#define OFF_GPK  (851968u)   // G bf16 frags: 131072
#define OFF_MPK  (983040u)   // M bf16 frags: 32768

#define SC_J 640.0f
#define SC_S 166.0f

__device__ __forceinline__ unsigned short f2bf(float f) {
  union { float f; unsigned u; } a; a.f = f;
  unsigned r = a.u + 0x7FFFu + ((a.u >> 16) & 1u);   // RNE bf16
  return (unsigned short)(r >> 16);
}
__device__ __forceinline__ float bf2f(unsigned short h) {
  union { unsigned u; float f; } a; a.u = ((unsigned)h) << 16;
  return a.f;
}
__device__ __forceinline__ float thr_of(float u) {   // spike <=> lamb > thr(u)
  return __builtin_fmaf(4.0f, __logf(u / (1.0f - u)), 0.4f);
}
__device__ __forceinline__ float fast_tanh_pos(float x) {  // x >= 0 here
  const float e2 = __expf(x + x);
  return 1.0f - 2.0f / (e2 + 1.0f);
}
// builtin i8 dot4 (AGPR-direct operands ok). Integer math order-invariant;
// identical trajectories to rounds 5-12.
__device__ __forceinline__ int sdot4(unsigned a, unsigned b, int acc) {
#if __has_builtin(__builtin_amdgcn_sdot4)
  return __builtin_amdgcn_sdot4((int)a, (int)b, acc, false);
#else
  int r;
  asm("v_dot4_i32_i8 %0, %1, %2, %3" : "=v"(r) : "v"(a), "v"(b), "v"(acc));
  return r;
#endif
}
template <int CTRL>
__device__ __forceinline__ int dpp_add(int x) {
  return x + __builtin_amdgcn_update_dpp(0, x, CTRL, 0xF, 0xF, true);
}
// 16-lane row reduce: xor1 (0xB1), xor2 (0x4E), 8-mirror (0x141), 16-mirror (0x140)
__device__ __forceinline__ int dpp_reduce16(int x) {
  return dpp_add<0x140>(dpp_add<0x141>(dpp_add<0x4E>(dpp_add<0xB1>(x))));
}

// ---------------- 1. jwm: G = W@J, M = W@Bw (fp32) ----------------
__launch_bounds__(512)
__global__ void jwm_kernel(const float* __restrict__ J, const float* __restrict__ Bw,
                           const float* __restrict__ W, unsigned char* __restrict__ ws) {
  __shared__ float wrow[512];
  const int o = blockIdx.x;
  const int tid = threadIdx.x;
  wrow[tid] = W[(size_t)o * 512 + tid];
  __syncthreads();
  const int k = tid, i = tid & 127;
  float g = 0.0f, m = 0.0f;
  for (int n = 0; n < 512; ++n) {
    const float wv = wrow[n];
    g = __builtin_fmaf(wv, J[(size_t)n * 512 + k], g);
    m = __builtin_fmaf(wv, Bw[(size_t)n * 128 + i], m);
  }
  ((float*)(ws + OFF_G))[(size_t)o * 512 + k] = g;
  if (tid < 128) ((float*)(ws + OFF_M))[(size_t)o * 128 + i] = m;
}

// ---------------- 2. pack ----------------
// JQK frag f = ((w*8 + i)*2 + j)*64 + l : lane l of wave w (w<16),
// neuron n = w*32 + (l>>4)*8 + i, slice kap = l&15,
// bytes J[n][32*kap + 16*j .. +16) i8.
__global__ void pack_kernel(const float* __restrict__ J, const float* __restrict__ Bw,
                            unsigned char* __restrict__ ws) {
  const int id = blockIdx.x * 256 + threadIdx.x;   // grid 136 -> 34816
  if (id < 16384) {
    const int f = id;
    const int l = f & 63, j = (f >> 6) & 1, i = (f >> 7) & 7, w = f >> 10;
    const int kap = l & 15;
    const int n = w * 32 + (l >> 4) * 8 + i;
    const int k0 = 32 * kap + 16 * j;
    unsigned dw[4];
#pragma unroll
    for (int d = 0; d < 4; ++d) {
      unsigned x = 0;
#pragma unroll
      for (int p = 0; p < 4; ++p) {
        const float jv = J[(size_t)n * 512 + k0 + 4 * d + p];
        int q = __float2int_rn(jv * SC_J);
        q = q > 127 ? 127 : (q < -127 ? -127 : q);
        x |= ((unsigned)(q & 255)) << (8 * p);
      }
      dw[d] = x;
    }
    uint4 out; out.x = dw[0]; out.y = dw[1]; out.z = dw[2]; out.w = dw[3];
    ((uint4*)(ws + OFF_JQK))[f] = out;
  } else if (id < 24576) {
    const int idx = id - 16384;         // (kt*4+g)*512 + n, kt<4
    const int n = idx & 511, kg = idx >> 9, k0 = kg * 8;
    unsigned short* bwh = (unsigned short*)(ws + OFF_BWH);
    unsigned short* bwl = (unsigned short*)(ws + OFF_BWL);
    for (int e = 0; e < 8; ++e) {
      const float x = Bw[(size_t)n * 128 + k0 + e];
      const unsigned short h = f2bf(x);
      bwh[(size_t)idx * 8 + e] = h;
      bwl[(size_t)idx * 8 + e] = f2bf(x - bf2f(h));
    }
  } else if (id < 32768) {
    const int idx = id - 24576;         // (kt*4+g)*128 + o, kt<16
    const int o = idx & 127, kg = idx >> 7, k0 = kg * 8;
    const float* G = (const float*)(ws + OFF_G);
    unsigned short* gpk = (unsigned short*)(ws + OFF_GPK);
    for (int e = 0; e < 8; ++e) gpk[(size_t)idx * 8 + e] = f2bf(G[(size_t)o * 512 + k0 + e]);
  } else {
    const int idx = id - 32768;         // (kt*4+g)*128 + o, kt<4
    const int o = idx & 127, kg = idx >> 7, k0 = kg * 8;
    const float* M = (const float*)(ws + OFF_M);
    unsigned short* mpk = (unsigned short*)(ws + OFF_MPK);
    for (int e = 0; e < 8; ++e) mpk[(size_t)idx * 8 + e] = f2bf(M[(size_t)o * 128 + k0 + e]);
  }
}

// ---------------- 3. xpd: D = thr(U) - X@Bw^T, SLOT layout ----------------
__launch_bounds__(256)
__global__ void xpd_kernel(const float* __restrict__ X, const float* __restrict__ U,
                           const unsigned char* __restrict__ ws, float* __restrict__ Dbuf) {
  __shared__ short Ah[64 * 136];
  __shared__ short Al[64 * 136];
  const unsigned short* bwh = (const unsigned short*)(ws + OFF_BWH);
  const unsigned short* bwl = (const unsigned short*)(ws + OFF_BWL);
  const int m0 = blockIdx.x * 64;
  const int n0 = blockIdx.y * 64;
  const int tid = threadIdx.x;
  for (int i = tid; i < 64 * 32; i += 256) {
    const int r = i >> 5, kq = i & 31;
    const float4 x4 = *(const float4*)(X + (size_t)(m0 + r) * 128 + kq * 4);
    short4 h4, l4; unsigned short h;
    h = f2bf(x4.x); h4.x = (short)h; l4.x = (short)f2bf(x4.x - bf2f(h));
    h = f2bf(x4.y); h4.y = (short)h; l4.y = (short)f2bf(x4.y - bf2f(h));
    h = f2bf(x4.z); h4.z = (short)h; l4.z = (short)f2bf(x4.z - bf2f(h));
    h = f2bf(x4.w); h4.w = (short)h; l4.w = (short)f2bf(x4.w - bf2f(h));
    *(short4*)(&Ah[r * 136 + kq * 4]) = h4;
    *(short4*)(&Al[r * 136 + kq * 4]) = l4;
  }
  __syncthreads();
  const int w = tid >> 6, l = tid & 63, lhi = l >> 4, llo = l & 15;
  const int rowA = 16 * w + llo;
  f32x4 a0 = {0,0,0,0}, a1 = {0,0,0,0}, a2 = {0,0,0,0}, a3 = {0,0,0,0};
#pragma unroll
  for (int kt = 0; kt < 4; ++kt) {
    const short8x ah = *(const short8x*)(&Ah[rowA * 136 + kt * 32 + lhi * 8]);
    const short8x al = *(const short8x*)(&Al[rowA * 136 + kt * 32 + lhi * 8]);
#define XT(TI, ACC) { \
    const size_t bi = ((size_t)((kt * 4 + lhi) * 512 + n0 + TI * 16 + llo)) * 8; \
    const short8x bh = *(const short8x*)(bwh + bi); \
    const short8x bl = *(const short8x*)(bwl + bi); \
    ACC = __builtin_amdgcn_mfma_f32_16x16x32_bf16(ah, bh, ACC, 0, 0, 0); \
    ACC = __builtin_amdgcn_mfma_f32_16x16x32_bf16(al, bh, ACC, 0, 0, 0); \
    ACC = __builtin_amdgcn_mfma_f32_16x16x32_bf16(ah, bl, ACC, 0, 0, 0); }
    XT(0, a0) XT(1, a1) XT(2, a2) XT(3, a3)
#undef XT
  }
  const int n = n0 + llo;
#pragma unroll
  for (int r = 0; r < 4; ++r) {
    const int bt = m0 + 16 * w + lhi * 4 + r;
    const int bb = bt >> 9, tt = bt & 511;
    const float* urow = U + (size_t)bt * 512;
    float* drow = Dbuf + ((size_t)bb * 513 + tt + 1) * 512;   // slot (b, t+1)
    drow[n]      = thr_of(urow[n])      - a0[r];
    drow[n + 16] = thr_of(urow[n + 16]) - a1[r];
    drow[n + 32] = thr_of(urow[n + 32]) - a2[r];
    drow[n + 48] = thr_of(urow[n + 48]) - a3[r];
  }
}

// ---------------- 4. recur: 128 WGs x 1024 thr (16 waves), 1 batch/WG ----------------
__launch_bounds__(1024)
__global__ void recur_kernel(const unsigned char* __restrict__ ws,
                             const float* __restrict__ Dv,
                             float* __restrict__ vtw, float* __restrict__ ztw) {
  __shared__ __align__(16) unsigned char s_sm[2][640];   // 8 blocks x 80B padded
  const int b = blockIdx.x;            // 1 batch per WG
  const int tid = threadIdx.x;
  const int w = tid >> 6, l = tid & 63;
  const int kap = l & 15;
  const int n_own = w * 32 + (l >> 4) * 8 + (l & 7);     // dup across l&8 pairs
  const int sm_wr = (n_own >> 6) * 80 + (n_own & 63);
  const int roff = (kap >> 1) * 80 + (kap & 1) * 32;

  // J frags: jr[i][j] = J[n_i][32*kap + 16*j ..), i8 x16; 64 VGPRs/lane.
  uint4 jr[8][2];
#pragma unroll
  for (int i = 0; i < 8; ++i)
#pragma unroll
    for (int j = 0; j < 2; ++j) {
      const unsigned char* p = ws + OFF_JQK +
          (size_t)(((w * 8 + i) * 2 + j) * 64 + l) * 16;
      asm volatile("global_load_dwordx4 %0, %1, off" : "=v"(jr[i][j]) : "v"(p));
    }
  asm volatile("s_waitcnt vmcnt(0)" ::: "memory");

  const float SC = 1.0f / (SC_J * SC_S);
  // t=0 slots
  if (tid < 512) {
    vtw[((size_t)b * 513) * 512 + tid] = 0.0f;
    ztw[((size_t)b * 513) * 512 + tid] = 0.0f;
  }

  const float* Dp = Dv + ((size_t)b * 513 + 1) * 512 + n_own;   // D slot base
  float* vbase = vtw + ((size_t)b * 513 + 1) * 512 + n_own;
  float* zbase = ztw + ((size_t)b * 513 + 1) * 512 + n_own;

  float dc[8];
#pragma unroll
  for (int i = 0; i < 8; ++i) dc[i] = Dp[(size_t)i * 512];

  unsigned zprev = 0u;
  float v0 = 0.0f, v1 = 0.1f;
  unsigned q0 = (unsigned)__float2int_rn(fast_tanh_pos(v0) * SC_S);
  unsigned q1 = (unsigned)__float2int_rn(fast_tanh_pos(v1) * SC_S);

  for (int c = 0; c < 64; ++c) {       // 64 sub-chunks x 8 steps
    const int t0 = c * 8;
    float v_arr[8];
    unsigned zbits = 0u;
#pragma unroll
    for (int i = 0; i < 8; ++i) {
      const int t = t0 + i;
      const unsigned q = zprev ? q1 : q0;
      const float v = zprev ? v1 : v0;
      v_arr[i] = v;
      if (!(l & 8)) s_sm[t & 1][sm_wr] = (unsigned char)q;
      asm volatile("s_waitcnt lgkmcnt(0)\n\ts_barrier" ::: "memory");
      // next-step candidates (overlap ds_read latency)
      v0 = 0.9f * v; v1 = v0 + 0.1f;
      q0 = (unsigned)__float2int_rn(fast_tanh_pos(v0) * SC_S);
      q1 = (unsigned)__float2int_rn(fast_tanh_pos(v1) * SC_S);
      // this lane's 32B s-slice (<=2-way banks, broadcast across groups)
      const unsigned char* sb = &s_sm[t & 1][0];
      const uint4 s0 = *(const uint4*)(sb + roff);
      const uint4 s1 = *(const uint4*)(sb + roff + 16);
      int a0 = 0, a1 = 0, a2 = 0, a3 = 0, a4 = 0, a5 = 0, a6 = 0, a7 = 0;
#define DOT(AI, I) \
      AI = sdot4(jr[I][0].x, s0.x, AI); AI = sdot4(jr[I][0].y, s0.y, AI); \
      AI = sdot4(jr[I][0].z, s0.z, AI); AI = sdot4(jr[I][0].w, s0.w, AI); \
      AI = sdot4(jr[I][1].x, s1.x, AI); AI = sdot4(jr[I][1].y, s1.y, AI); \
      AI = sdot4(jr[I][1].z, s1.z, AI); AI = sdot4(jr[I][1].w, s1.w, AI);
      DOT(a0, 0) DOT(a1, 1) DOT(a2, 2) DOT(a3, 3)
      DOT(a4, 4) DOT(a5, 5) DOT(a6, 6) DOT(a7, 7)
#undef DOT
      a0 = dpp_reduce16(a0); a1 = dpp_reduce16(a1);
      a2 = dpp_reduce16(a2); a3 = dpp_reduce16(a3);
      a4 = dpp_reduce16(a4); a5 = dpp_reduce16(a5);
      a6 = dpp_reduce16(a6); a7 = dpp_reduce16(a7);
      // select own neuron: in-group index = l&7
      const int q01 = (l & 1) ? a1 : a0;
      const int q23 = (l & 1) ? a3 : a2;
      const int q45 = (l & 1) ? a5 : a4;
      const int q67 = (l & 1) ? a7 : a6;
      const int r0 = (l & 2) ? q23 : q01;
      const int r1 = (l & 2) ? q67 : q45;
      const int accv = (l & 4) ? r1 : r0;
      const float lam = (float)accv * SC;
      const unsigned z = (lam > dc[i]) ? 1u : 0u;
      zbits |= z << i;
      zprev = z;
      // refill D for step t0+8+i (slot t0+9+i, disjoint from this chunk's
      // stores at slots t0+1..t0+8; tail over-read lands in zt region, unused)
      dc[i] = Dp[(size_t)(t0 + 8 + i) * 512];
    }
    // ---- bulk store after ALL dc uses; zprev depends on dc[7] -> opaque-zero
    // orders the stores after the D consumption. l&8 halves split v/z duty.
    unsigned zzero;
    asm("v_and_b32 %0, 0, %1" : "=v"(zzero) : "v"(zprev));
    if (!(l & 8)) {
      float* vst = vbase + (size_t)t0 * 512 + zzero;
#pragma unroll
      for (int i = 0; i < 8; ++i) vst[(size_t)i * 512] = v_arr[i];
    } else {
      float* zst = zbase + (size_t)t0 * 512 + zzero;
#pragma unroll
      for (int i = 0; i < 8; ++i) zst[(size_t)i * 512] = ((zbits >> i) & 1u) ? 1.0f : 0.0f;
    }
  }
}

// ---------------- 5. outk: out = tanh(vt)@G^T + X@M^T ----------------
__launch_bounds__(512)
__global__ void outk_kernel(const float* __restrict__ X, const float* __restrict__ vt,
                            const unsigned char* __restrict__ ws,
                            float* __restrict__ op) {
  __shared__ unsigned short sl[64 * 520];    // s bf16 [64 t][512 n]
  __shared__ unsigned short xl[64 * 136];    // X bf16 [64 t][128 i]
  const int m0 = blockIdx.x * 64;            // bt rows
  const int tid = threadIdx.x;
  const int w = tid >> 6, l = tid & 63, lhi = l >> 4, llo = l & 15;
  const unsigned short* gpk = (const unsigned short*)(ws + OFF_GPK);
  const unsigned short* mpk = (const unsigned short*)(ws + OFF_MPK);

#pragma unroll 4
  for (int r = 0; r < 64; ++r) {
    const int bt = m0 + r, b = bt >> 9, t = bt & 511;
    const float v = vt[((size_t)b * 513 + t + 1) * 512 + tid];
    sl[r * 520 + tid] = f2bf(fast_tanh_pos(v));
  }
#pragma unroll
  for (int i = 0; i < 16; ++i) {
    const int idx = i * 512 + tid;
    const int r = idx >> 7, c = idx & 127;
    const int bt = m0 + r;
    xl[r * 136 + c] = f2bf(X[(size_t)bt * 128 + c]);
  }
  __syncthreads();
  const int m = w >> 1, oh = (w & 1) * 4;
  f32x4 a0 = {0,0,0,0}, a1 = {0,0,0,0}, a2 = {0,0,0,0}, a3 = {0,0,0,0};
#pragma unroll
  for (int kt = 0; kt < 16; ++kt) {
    const short8x A = *(const short8x*)(sl + (m * 16 + llo) * 520 + kt * 32 + lhi * 8);
#define GT(TI, ACC) { \
    const short8x B = *(const short8x*)(gpk + ((size_t)((kt * 4 + lhi) * 128 + (oh + TI) * 16 + llo)) * 8); \
    ACC = __builtin_amdgcn_mfma_f32_16x16x32_bf16(A, B, ACC, 0, 0, 0); }
    GT(0, a0) GT(1, a1) GT(2, a2) GT(3, a3)
#undef GT
  }
#pragma unroll
  for (int kt = 0; kt < 4; ++kt) {
    const short8x A = *(const short8x*)(xl + (m * 16 + llo) * 136 + kt * 32 + lhi * 8);
#define MT(TI, ACC) { \
    const short8x B = *(const short8x*)(mpk + ((size_t)((kt * 4 + lhi) * 128 + (oh + TI) * 16 + llo)) * 8); \
    ACC = __builtin_amdgcn_mfma_f32_16x16x32_bf16(A, B, ACC, 0, 0, 0); }
    MT(0, a0) MT(1, a1) MT(2, a2) MT(3, a3)
#undef MT
  }
  float* obase = op + ((size_t)(m0 + m * 16 + lhi * 4)) * 128 + llo;
#pragma unroll
  for (int r = 0; r < 4; ++r) {
    float* orow = obase + (size_t)r * 128;
    orow[(oh + 0) * 16] = a0[r];
    orow[(oh + 1) * 16] = a1[r];
    orow[(oh + 2) * 16] = a2[r];
    orow[(oh + 3) * 16] = a3[r];
  }
}

extern "C" void kernel_launch(void* const* d_in, const int* in_sizes, int n_in,
                              void* d_out, int out_size, void* d_ws, size_t ws_size,
                              hipStream_t stream) {
  const float* X  = (const float*)d_in[0];   // inputs [128,512,128]
  const float* U  = (const float*)d_in[1];   // rand_u [128,512,512]
  const float* J  = (const float*)d_in[2];   // [512,512]
  const float* Bw = (const float*)d_in[3];   // [512,128]
  const float* W  = (const float*)d_in[4];   // [128,512]
  float* vt = (float*)d_out;
  float* zt = vt + (size_t)128 * 513 * 512;
  float* op = vt + (size_t)2 * 128 * 513 * 512;
  unsigned char* ws = (unsigned char*)d_ws;

  jwm_kernel<<<128, 512, 0, stream>>>(J, Bw, W, ws);
  pack_kernel<<<136, 256, 0, stream>>>(J, Bw, ws);
  xpd_kernel<<<dim3(1024, 8), 256, 0, stream>>>(X, U, ws, vt);   // D -> vt slots
  recur_kernel<<<128, 1024, 0, stream>>>(ws, vt, vt, zt);
  outk_kernel<<<1024, 512, 0, stream>>>(X, vt, ws, op);
}